// Round 4
// baseline (128.608 us; speedup 1.0000x reference)
//
#include <hip/hip_runtime.h>
#include <math.h>

typedef __bf16 bf16;
typedef __bf16 bf16x4 __attribute__((ext_vector_type(4)));
typedef __bf16 bf16x8 __attribute__((ext_vector_type(8)));
typedef float f32x4 __attribute__((ext_vector_type(4)));

#define MFMA16(a,b,c) __builtin_amdgcn_mfma_f32_16x16x32_bf16((a),(b),(c),0,0,0)

static constexpr int HS  = 64;    // head size
static constexpr int SEQ = 2048;  // sequence length
static constexpr int NE  = 1024;  // n_embed
static constexpr int NB  = 8;     // batch

__device__ __forceinline__ bf16x8 cvt8(float4 a, float4 b) {
  bf16x8 r;
  r[0]=(bf16)a.x; r[1]=(bf16)a.y; r[2]=(bf16)a.z; r[3]=(bf16)a.w;
  r[4]=(bf16)b.x; r[5]=(bf16)b.y; r[6]=(bf16)b.z; r[7]=(bf16)b.w;
  return r;
}

// ---- W f32 -> bf16 (Wq pre-scaled by 1/sqrt(64)) ----
__global__ __launch_bounds__(256) void wcvt_kernel(
    const float* __restrict__ Wq, const float* __restrict__ Wk,
    const float* __restrict__ Wv, bf16* __restrict__ wqb,
    bf16* __restrict__ wkb, bf16* __restrict__ wvb)
{
  int i = (blockIdx.x * 256 + threadIdx.x) * 4;   // 64 blocks -> 65536 elems
  float4 q = *(const float4*)(Wq + i);
  float4 k = *(const float4*)(Wk + i);
  float4 v = *(const float4*)(Wv + i);
  bf16x4 qo, ko, vo;
  qo[0]=(bf16)(q.x*0.125f); qo[1]=(bf16)(q.y*0.125f); qo[2]=(bf16)(q.z*0.125f); qo[3]=(bf16)(q.w*0.125f);
  ko[0]=(bf16)k.x; ko[1]=(bf16)k.y; ko[2]=(bf16)k.z; ko[3]=(bf16)k.w;
  vo[0]=(bf16)v.x; vo[1]=(bf16)v.y; vo[2]=(bf16)v.z; vo[3]=(bf16)v.w;
  *(bf16x4*)(wqb + i) = qo;
  *(bf16x4*)(wkb + i) = ko;
  *(bf16x4*)(wvb + i) = vo;
}

// ---- projection: barrier-less, LDS-less ----
// grid 512 x 256thr. Blocks 0..255: Q from index. 256..511: K+V from memory.
// Wave w owns rows slab*64 + 16w .. +15. W b-frags read direct from bf16 W
// (L1-broadcast across the 4 waves); A rows f32 -> reg -> cvt.
template<int KV>
__device__ __forceinline__ void proj_body(
    const float* __restrict__ X, const bf16* __restrict__ W0,
    const bf16* __restrict__ W1, bf16* __restrict__ out0,
    bf16* __restrict__ outVT, int slab)
{
  const int tid  = threadIdx.x;
  const int lane = tid & 63;
  const int w    = tid >> 6;
  const int m    = lane & 15;
  const int g    = lane >> 4;
  const int rowBase = slab * 64 + 16 * w;

  const float* xr = X + (size_t)(rowBase + m) * NE + g * 8;
  const bf16*  w0 = W0 + (size_t)m * NE + g * 8;   // + 16n*NE + kt*64 (+32 for kk=1)
  const bf16*  w1 = KV ? (W1 + (size_t)m * NE + g * 8) : nullptr;

  const f32x4 vz = {0.f,0.f,0.f,0.f};
  f32x4 accA[4] = {vz, vz, vz, vz};
  f32x4 accB[4] = {vz, vz, vz, vz};

#pragma unroll 2
  for (int kt = 0; kt < 16; ++kt) {
    const float* p = xr + kt * 64;
    float4 a0 = *(const float4*)(p);
    float4 a1 = *(const float4*)(p + 4);
    float4 a2 = *(const float4*)(p + 32);
    float4 a3 = *(const float4*)(p + 36);
    bf16x8 af0 = cvt8(a0, a1);
    bf16x8 af1 = cvt8(a2, a3);
#pragma unroll
    for (int n = 0; n < 4; ++n) {
      const bf16* r0 = w0 + (size_t)(16*n) * NE + kt * 64;
      bf16x8 b00 = *(const bf16x8*)(r0);
      bf16x8 b01 = *(const bf16x8*)(r0 + 32);
      accA[n] = MFMA16(af0, b00, accA[n]);
      accA[n] = MFMA16(af1, b01, accA[n]);
      if (KV) {
        const bf16* r1 = w1 + (size_t)(16*n) * NE + kt * 64;
        bf16x8 b10 = *(const bf16x8*)(r1);
        bf16x8 b11 = *(const bf16x8*)(r1 + 32);
        accB[n] = MFMA16(af0, b10, accB[n]);
        accB[n] = MFMA16(af1, b11, accB[n]);
      }
    }
  }

  // C/D: col = lane&15, row = 4*(lane>>4)+i  [m89-verified]
#pragma unroll
  for (int n = 0; n < 4; ++n)
#pragma unroll
    for (int i = 0; i < 4; ++i) {
      int row = rowBase + 4*g + i;
      int h   = 16*n + m;
      out0[(size_t)row * HS + h] = (bf16)accA[n][i];
      if (KV)
        outVT[((size_t)(row >> 11) * HS + h) * SEQ + (row & 2047)] =
            (bf16)accB[n][i];
    }
}

__global__ __launch_bounds__(256, 2) void proj_kernel(
    const float* __restrict__ index, const float* __restrict__ memory,
    const bf16* __restrict__ wqb, const bf16* __restrict__ wkb,
    const bf16* __restrict__ wvb, bf16* __restrict__ qb,
    bf16* __restrict__ kb, bf16* __restrict__ vtb)
{
  if (blockIdx.x < 256)
    proj_body<0>(index,  wqb, nullptr, qb, nullptr, blockIdx.x);
  else
    proj_body<1>(memory, wkb, wvb,     kb, vtb, blockIdx.x - 256);
}

// ---- flash attention: wave-split kv, barrier-less main loop ----
// Block = 128 thr (2 waves) owns 16 q-rows (QBLK=16). Wave w processes kv
// tiles j = w, w+2, ... with its OWN single-buffered LDS K/V tile + register
// prefetch -> no __syncthreads in the loop. One final barrier merges the two
// online-softmax partials in LDS.
__global__ __launch_bounds__(128, 2) void attn_kernel(
    const bf16* __restrict__ qb, const bf16* __restrict__ kb,
    const bf16* __restrict__ vtb, float* __restrict__ out)
{
  __shared__ __align__(16) bf16 Ks[2][64][72];    // per-wave K tile [kv][d]
  __shared__ __align__(16) bf16 VTs[2][64][72];   // per-wave V^T tile [d][kv]
  __shared__ __align__(16) bf16 Ps[2][16][72];    // per-wave P

  const int tid  = threadIdx.x;
  const int lane = tid & 63;
  const int w    = tid >> 6;
  const int m    = lane & 15;
  const int g    = lane >> 4;
  const int qt   = 127 - blockIdx.x;   // reversed: longest blocks first
  const int b    = blockIdx.y;
  const int nkv  = (qt >> 2) + 1;      // kv tiles of 64 covering rows <= qt*16+15
  const int r0   = lane >> 1;          // prefetch: row pair base
  const int hh   = (lane & 1) * 32;    // prefetch: 32-elem half (64B)

  // Q fragments (rows qt*16+m; scale pre-baked into Wq)
  bf16x8 qf0 = *(const bf16x8*)(qb + ((size_t)b*SEQ + qt*16 + m)*HS + g*8);
  bf16x8 qf1 = *(const bf16x8*)(qb + ((size_t)b*SEQ + qt*16 + m)*HS + 32 + g*8);

  const f32x4 vz = {0.f,0.f,0.f,0.f};
  f32x4 o_acc[4] = {vz, vz, vz, vz};
  float mrun[4], lrun[4];
#pragma unroll
  for (int i = 0; i < 4; ++i) { mrun[i] = -INFINITY; lrun[i] = 0.f; }

  bf16x8 kp[8], vp[8];
  const bf16* kbB = kb  + (size_t)b*SEQ*HS;
  const bf16* vtB = vtb + (size_t)b*HS*SEQ;

  auto loadKV = [&](int j) {
    const bf16* kt_ = kbB + (size_t)j*64*HS;      // row r: + r*64
    const bf16* vt_ = vtB + j*64;                 // row h: + h*SEQ
#pragma unroll
    for (int q = 0; q < 4; ++q) {
      kp[q]   = *(const bf16x8*)(kt_ + (size_t)r0*64        + hh + q*8);
      kp[4+q] = *(const bf16x8*)(kt_ + (size_t)(r0+32)*64   + hh + q*8);
      vp[q]   = *(const bf16x8*)(vt_ + (size_t)r0*SEQ       + hh + q*8);
      vp[4+q] = *(const bf16x8*)(vt_ + (size_t)(r0+32)*SEQ  + hh + q*8);
    }
  };
  auto writeKV = [&]() {
#pragma unroll
    for (int q = 0; q < 4; ++q) {
      *(bf16x8*)&Ks[w][r0][hh + q*8]      = kp[q];
      *(bf16x8*)&Ks[w][r0+32][hh + q*8]   = kp[4+q];
      *(bf16x8*)&VTs[w][r0][hh + q*8]     = vp[q];
      *(bf16x8*)&VTs[w][r0+32][hh + q*8]  = vp[4+q];
    }
  };

  int j = w;
  if (j < nkv) {
    loadKV(j);
    writeKV();
    while (true) {
      const int jn = j + 2;
      const bool more = jn < nkv;
      if (more) loadKV(jn);      // issue early: hides under compute (T14)

      // S = Q.K^T
      f32x4 s_acc[4];
#pragma unroll
      for (int n = 0; n < 4; ++n) {
        f32x4 z = vz;
        z = MFMA16(qf0, *(const bf16x8*)&Ks[w][16*n + m][g*8], z);
        z = MFMA16(qf1, *(const bf16x8*)&Ks[w][16*n + m][32 + g*8], z);
        s_acc[n] = z;
      }
      if (j == nkv - 1) {   // diagonal tile: causal mask
#pragma unroll
        for (int n = 0; n < 4; ++n) {
          int gk = j*64 + 16*n + m;
#pragma unroll
          for (int i = 0; i < 4; ++i)
            if (gk > qt*16 + 4*g + i) s_acc[n][i] = -INFINITY;
        }
      }

      // online softmax (rows 4g+i; reduce over 16 m-lanes)
      float corr[4], tsum[4];
#pragma unroll
      for (int i = 0; i < 4; ++i) {
        float mx = fmaxf(fmaxf(s_acc[0][i], s_acc[1][i]),
                         fmaxf(s_acc[2][i], s_acc[3][i]));
        mx = fmaxf(mx, __shfl_xor(mx, 1));
        mx = fmaxf(mx, __shfl_xor(mx, 2));
        mx = fmaxf(mx, __shfl_xor(mx, 4));
        mx = fmaxf(mx, __shfl_xor(mx, 8));
        float mnew = fmaxf(mrun[i], mx);
        corr[i] = __expf(mrun[i] - mnew);
        mrun[i] = mnew;
        tsum[i] = 0.f;
      }
#pragma unroll
      for (int n = 0; n < 4; ++n)
#pragma unroll
        for (int i = 0; i < 4; ++i) {
          float p = __expf(s_acc[n][i] - mrun[i]);
          tsum[i] += p;
          Ps[w][4*g + i][16*n + m] = (bf16)p;
        }
#pragma unroll
      for (int i = 0; i < 4; ++i) {
        float s = tsum[i];
        s += __shfl_xor(s, 1);
        s += __shfl_xor(s, 2);
        s += __shfl_xor(s, 4);
        s += __shfl_xor(s, 8);
        lrun[i] = lrun[i] * corr[i] + s;
      }
#pragma unroll
      for (int n = 0; n < 4; ++n)
#pragma unroll
        for (int i = 0; i < 4; ++i) o_acc[n][i] *= corr[i];

      // O += P.V
#pragma unroll
      for (int kk = 0; kk < 2; ++kk) {
        bf16x8 pf = *(const bf16x8*)&Ps[w][m][kk*32 + g*8];
#pragma unroll
        for (int n = 0; n < 4; ++n) {
          bf16x8 vf = *(const bf16x8*)&VTs[w][16*n + m][kk*32 + g*8];
          o_acc[n] = MFMA16(pf, vf, o_acc[n]);
        }
      }

      if (!more) break;
      writeKV();               // same-wave DS ops are in-order: safe overwrite
      j = jn;
    }
  }

  // ---- cross-wave merge of the two online-softmax partials ----
  float* PO = (float*)&Ks[w][0][0];    // 16x64 f32 partial O (4 KB, fits)
  float* PM = (float*)&VTs[w][0][0];   // m[16], l[16]
#pragma unroll
  for (int n = 0; n < 4; ++n)
#pragma unroll
    for (int i = 0; i < 4; ++i)
      PO[(4*g + i)*64 + 16*n + m] = o_acc[n][i];
  if (m == 0) {
#pragma unroll
    for (int i = 0; i < 4; ++i) {
      PM[4*g + i]      = mrun[i];
      PM[16 + 4*g + i] = lrun[i];
    }
  }
  __syncthreads();

  {
    const int r  = tid >> 3;           // 0..15
    const int c0 = (tid & 7) * 8;
    const float* O0 = (const float*)&Ks[0][0][0];
    const float* O1 = (const float*)&Ks[1][0][0];
    const float* M0 = (const float*)&VTs[0][0][0];
    const float* M1 = (const float*)&VTs[1][0][0];
    float m0 = M0[r], l0 = M0[16 + r];
    float m1 = M1[r], l1 = M1[16 + r];
    float mx = fmaxf(m0, m1);
    float s0 = __expf(m0 - mx), s1 = __expf(m1 - mx);   // exp(-inf)=0
    float inv = 1.f / (s0*l0 + s1*l1);
    float4 x0 = *(const float4*)(O0 + r*64 + c0);
    float4 x1 = *(const float4*)(O0 + r*64 + c0 + 4);
    float4 y0 = *(const float4*)(O1 + r*64 + c0);
    float4 y1 = *(const float4*)(O1 + r*64 + c0 + 4);
    float4 o0, o1;
    o0.x=(x0.x*s0+y0.x*s1)*inv; o0.y=(x0.y*s0+y0.y*s1)*inv;
    o0.z=(x0.z*s0+y0.z*s1)*inv; o0.w=(x0.w*s0+y0.w*s1)*inv;
    o1.x=(x1.x*s0+y1.x*s1)*inv; o1.y=(x1.y*s0+y1.y*s1)*inv;
    o1.z=(x1.z*s0+y1.z*s1)*inv; o1.w=(x1.w*s0+y1.w*s1)*inv;
    float* op = out + ((size_t)b*SEQ + qt*16 + r) * HS + c0;
    *(float4*)(op)     = o0;
    *(float4*)(op + 4) = o1;
  }
}

extern "C" void kernel_launch(void* const* d_in, const int* in_sizes, int n_in,
                              void* d_out, int out_size, void* d_ws, size_t ws_size,
                              hipStream_t stream) {
  (void)in_sizes; (void)n_in; (void)out_size; (void)ws_size;
  const float* index  = (const float*)d_in[0];
  const float* memory = (const float*)d_in[1];
  const float* Wq     = (const float*)d_in[2];
  const float* Wk     = (const float*)d_in[3];
  const float* Wv     = (const float*)d_in[4];
  float* out = (float*)d_out;

  bf16* qb  = (bf16*)d_ws;                          // [NB*SEQ][64]
  bf16* kb  = qb  + (size_t)NB * SEQ * HS;          // [NB*SEQ][64]
  bf16* vtb = kb  + (size_t)NB * SEQ * HS;          // [NB][64][SEQ]
  bf16* wqb = vtb + (size_t)NB * SEQ * HS;          // [64][1024] (pre-scaled)
  bf16* wkb = wqb + (size_t)HS * NE;
  bf16* wvb = wkb + (size_t)HS * NE;

  wcvt_kernel<<<dim3(64), 256, 0, stream>>>(Wq, Wk, Wv, wqb, wkb, wvb);
  proj_kernel<<<dim3(512), 256, 0, stream>>>(index, memory, wqb, wkb, wvb, qb, kb, vtb);
  attn_kernel<<<dim3(128, 8), 128, 0, stream>>>(qb, kb, vtb, out);
}

// Round 5
// 81.067 us; speedup vs baseline: 1.5864x; 1.5864x over previous
//
#include <hip/hip_runtime.h>
#include <math.h>

typedef __bf16 bf16;
typedef __bf16 bf16x4 __attribute__((ext_vector_type(4)));
typedef __bf16 bf16x8 __attribute__((ext_vector_type(8)));
typedef float f32x4 __attribute__((ext_vector_type(4)));

#define MFMA16(a,b,c) __builtin_amdgcn_mfma_f32_16x16x32_bf16((a),(b),(c),0,0,0)

static constexpr int HS  = 64;    // head size
static constexpr int SEQ = 2048;  // sequence length
static constexpr int NE  = 1024;  // n_embed
static constexpr int NB  = 8;     // batch

__device__ __forceinline__ bf16x8 cvt8(float4 a, float4 b) {
  bf16x8 r;
  r[0]=(bf16)a.x; r[1]=(bf16)a.y; r[2]=(bf16)a.z; r[3]=(bf16)a.w;
  r[4]=(bf16)b.x; r[5]=(bf16)b.y; r[6]=(bf16)b.z; r[7]=(bf16)b.w;
  return r;
}

// ---- W f32 -> bf16 (Wq pre-scaled by 1/sqrt(64)) ----
__global__ __launch_bounds__(256) void wcvt_kernel(
    const float* __restrict__ Wq, const float* __restrict__ Wk,
    const float* __restrict__ Wv, bf16* __restrict__ wqb,
    bf16* __restrict__ wkb, bf16* __restrict__ wvb)
{
  int i = (blockIdx.x * 256 + threadIdx.x) * 4;   // 64 blocks -> 65536 elems
  float4 q = *(const float4*)(Wq + i);
  float4 k = *(const float4*)(Wk + i);
  float4 v = *(const float4*)(Wv + i);
  bf16x4 qo, ko, vo;
  qo[0]=(bf16)(q.x*0.125f); qo[1]=(bf16)(q.y*0.125f); qo[2]=(bf16)(q.z*0.125f); qo[3]=(bf16)(q.w*0.125f);
  ko[0]=(bf16)k.x; ko[1]=(bf16)k.y; ko[2]=(bf16)k.z; ko[3]=(bf16)k.w;
  vo[0]=(bf16)v.x; vo[1]=(bf16)v.y; vo[2]=(bf16)v.z; vo[3]=(bf16)v.w;
  *(bf16x4*)(wqb + i) = qo;
  *(bf16x4*)(wkb + i) = ko;
  *(bf16x4*)(wvb + i) = vo;
}

// ---- projection: LDS-staged, double-buffered, issue-early/write-late ----
// grid 512 x 256thr (4 waves). Blocks 0..255: Q from index; 256..511: K+V.
// Per K-step (BK=64): coalesced global loads -> regs (issued BEFORE compute),
// compute current buffer (ds_read + MFMA), then ds_write the next buffer
// (vmcnt wait overlaps compute), one barrier. 2 blocks/CU fill barrier waits.
template<int KV>
__device__ __forceinline__ void proj_body(
    const float* __restrict__ X, const bf16* __restrict__ W0,
    const bf16* __restrict__ W1, bf16* __restrict__ out0,
    bf16* __restrict__ outVT, int slab,
    bf16 (*Xs)[64][72], bf16 (*W0s)[64][72], bf16 (*W1s)[64][72])
{
  const int tid  = threadIdx.x;
  const int lane = tid & 63;
  const int w    = tid >> 6;
  const int m    = lane & 15;
  const int g    = lane >> 4;
  const int rowBase = slab * 64;
  const int srow = tid >> 2;          // staging row 0..63
  const int sseg = (tid & 3) * 16;    // staging 16-col segment

  const float* xp  = X  + (size_t)(rowBase + srow) * NE + sseg;  // + kt*64
  const bf16*  w0p = W0 + (size_t)srow * NE + sseg;
  const bf16*  w1p = KV ? (W1 + (size_t)srow * NE + sseg) : nullptr;

  const f32x4 vz = {0.f,0.f,0.f,0.f};
  f32x4 accA[4] = {vz, vz, vz, vz};
  f32x4 accB[4] = {vz, vz, vz, vz};   // DCE'd when !KV

  float4 xa, xb, xc, xd;              // X stage regs (16 f32)
  bf16x8 wa0, wa1, wb0, wb1;          // W stage regs

  auto loadT = [&](int kt) {
    const float* p = xp + kt * 64;
    xa = *(const float4*)(p);
    xb = *(const float4*)(p + 4);
    xc = *(const float4*)(p + 8);
    xd = *(const float4*)(p + 12);
    const bf16* q0 = w0p + kt * 64;
    wa0 = *(const bf16x8*)(q0);
    wa1 = *(const bf16x8*)(q0 + 8);
    if (KV) {
      const bf16* q1 = w1p + kt * 64;
      wb0 = *(const bf16x8*)(q1);
      wb1 = *(const bf16x8*)(q1 + 8);
    }
  };
  auto writeT = [&](int buf) {
    *(bf16x8*)&Xs[buf][srow][sseg]      = cvt8(xa, xb);
    *(bf16x8*)&Xs[buf][srow][sseg + 8]  = cvt8(xc, xd);
    *(bf16x8*)&W0s[buf][srow][sseg]     = wa0;
    *(bf16x8*)&W0s[buf][srow][sseg + 8] = wa1;
    if (KV) {
      *(bf16x8*)&W1s[buf][srow][sseg]     = wb0;
      *(bf16x8*)&W1s[buf][srow][sseg + 8] = wb1;
    }
  };
  auto compute = [&](int buf) {
#pragma unroll
    for (int kk = 0; kk < 2; ++kk) {
      bf16x8 af = *(const bf16x8*)&Xs[buf][16*w + m][kk*32 + g*8];
#pragma unroll
      for (int n = 0; n < 4; ++n) {
        bf16x8 b0 = *(const bf16x8*)&W0s[buf][16*n + m][kk*32 + g*8];
        accA[n] = MFMA16(af, b0, accA[n]);
        if (KV) {
          bf16x8 b1 = *(const bf16x8*)&W1s[buf][16*n + m][kk*32 + g*8];
          accB[n] = MFMA16(af, b1, accB[n]);
        }
      }
    }
  };

  loadT(0);
  writeT(0);
  __syncthreads();

  for (int kt = 0; kt < 16; kt += 2) {
    if (kt + 1 < 16) loadT(kt + 1);   // issue early: hides under compute
    compute(0);
    if (kt + 1 < 16) writeT(1);       // vmcnt wait lands after MFMA phase
    __syncthreads();
    if (kt + 2 < 16) loadT(kt + 2);
    compute(1);
    if (kt + 2 < 16) writeT(0);
    __syncthreads();
  }

  // C/D: col = lane&15, row = 4*(lane>>4)+i  [m89-verified]
#pragma unroll
  for (int n = 0; n < 4; ++n)
#pragma unroll
    for (int i = 0; i < 4; ++i) {
      int row = rowBase + 16*w + 4*g + i;
      int h   = 16*n + m;
      out0[(size_t)row * HS + h] = (bf16)accA[n][i];
      if (KV)
        outVT[((size_t)(row >> 11) * HS + h) * SEQ + (row & 2047)] =
            (bf16)accB[n][i];
    }
}

__global__ __launch_bounds__(256, 2) void proj_kernel(
    const float* __restrict__ index, const float* __restrict__ memory,
    const bf16* __restrict__ wqb, const bf16* __restrict__ wkb,
    const bf16* __restrict__ wvb, bf16* __restrict__ qb,
    bf16* __restrict__ kb, bf16* __restrict__ vtb)
{
  __shared__ __align__(16) bf16 Xs[2][64][72];    // 18.4 KB
  __shared__ __align__(16) bf16 W0s[2][64][72];
  __shared__ __align__(16) bf16 W1s[2][64][72];   // total 55.3 KB -> 2 blk/CU
  if (blockIdx.x < 256)
    proj_body<0>(index,  wqb, nullptr, qb, nullptr, blockIdx.x, Xs, W0s, W1s);
  else
    proj_body<1>(memory, wkb, wvb,     kb, vtb, blockIdx.x - 256, Xs, W0s, W1s);
}

// ---- flash attention: wave-split kv, barrier-less main loop (unchanged R4) ----
__global__ __launch_bounds__(128, 2) void attn_kernel(
    const bf16* __restrict__ qb, const bf16* __restrict__ kb,
    const bf16* __restrict__ vtb, float* __restrict__ out)
{
  __shared__ __align__(16) bf16 Ks[2][64][72];    // per-wave K tile [kv][d]
  __shared__ __align__(16) bf16 VTs[2][64][72];   // per-wave V^T tile [d][kv]
  __shared__ __align__(16) bf16 Ps[2][16][72];    // per-wave P

  const int tid  = threadIdx.x;
  const int lane = tid & 63;
  const int w    = tid >> 6;
  const int m    = lane & 15;
  const int g    = lane >> 4;
  const int qt   = 127 - blockIdx.x;   // reversed: longest blocks first
  const int b    = blockIdx.y;
  const int nkv  = (qt >> 2) + 1;      // kv tiles of 64 covering rows <= qt*16+15
  const int r0   = lane >> 1;
  const int hh   = (lane & 1) * 32;

  bf16x8 qf0 = *(const bf16x8*)(qb + ((size_t)b*SEQ + qt*16 + m)*HS + g*8);
  bf16x8 qf1 = *(const bf16x8*)(qb + ((size_t)b*SEQ + qt*16 + m)*HS + 32 + g*8);

  const f32x4 vz = {0.f,0.f,0.f,0.f};
  f32x4 o_acc[4] = {vz, vz, vz, vz};
  float mrun[4], lrun[4];
#pragma unroll
  for (int i = 0; i < 4; ++i) { mrun[i] = -INFINITY; lrun[i] = 0.f; }

  bf16x8 kp[8], vp[8];
  const bf16* kbB = kb  + (size_t)b*SEQ*HS;
  const bf16* vtB = vtb + (size_t)b*HS*SEQ;

  auto loadKV = [&](int j) {
    const bf16* kt_ = kbB + (size_t)j*64*HS;
    const bf16* vt_ = vtB + j*64;
#pragma unroll
    for (int q = 0; q < 4; ++q) {
      kp[q]   = *(const bf16x8*)(kt_ + (size_t)r0*64        + hh + q*8);
      kp[4+q] = *(const bf16x8*)(kt_ + (size_t)(r0+32)*64   + hh + q*8);
      vp[q]   = *(const bf16x8*)(vt_ + (size_t)r0*SEQ       + hh + q*8);
      vp[4+q] = *(const bf16x8*)(vt_ + (size_t)(r0+32)*SEQ  + hh + q*8);
    }
  };
  auto writeKV = [&]() {
#pragma unroll
    for (int q = 0; q < 4; ++q) {
      *(bf16x8*)&Ks[w][r0][hh + q*8]      = kp[q];
      *(bf16x8*)&Ks[w][r0+32][hh + q*8]   = kp[4+q];
      *(bf16x8*)&VTs[w][r0][hh + q*8]     = vp[q];
      *(bf16x8*)&VTs[w][r0+32][hh + q*8]  = vp[4+q];
    }
  };

  int j = w;
  if (j < nkv) {
    loadKV(j);
    writeKV();
    while (true) {
      const int jn = j + 2;
      const bool more = jn < nkv;
      if (more) loadKV(jn);

      f32x4 s_acc[4];
#pragma unroll
      for (int n = 0; n < 4; ++n) {
        f32x4 z = vz;
        z = MFMA16(qf0, *(const bf16x8*)&Ks[w][16*n + m][g*8], z);
        z = MFMA16(qf1, *(const bf16x8*)&Ks[w][16*n + m][32 + g*8], z);
        s_acc[n] = z;
      }
      if (j == nkv - 1) {
#pragma unroll
        for (int n = 0; n < 4; ++n) {
          int gk = j*64 + 16*n + m;
#pragma unroll
          for (int i = 0; i < 4; ++i)
            if (gk > qt*16 + 4*g + i) s_acc[n][i] = -INFINITY;
        }
      }

      float corr[4], tsum[4];
#pragma unroll
      for (int i = 0; i < 4; ++i) {
        float mx = fmaxf(fmaxf(s_acc[0][i], s_acc[1][i]),
                         fmaxf(s_acc[2][i], s_acc[3][i]));
        mx = fmaxf(mx, __shfl_xor(mx, 1));
        mx = fmaxf(mx, __shfl_xor(mx, 2));
        mx = fmaxf(mx, __shfl_xor(mx, 4));
        mx = fmaxf(mx, __shfl_xor(mx, 8));
        float mnew = fmaxf(mrun[i], mx);
        corr[i] = __expf(mrun[i] - mnew);
        mrun[i] = mnew;
        tsum[i] = 0.f;
      }
#pragma unroll
      for (int n = 0; n < 4; ++n)
#pragma unroll
        for (int i = 0; i < 4; ++i) {
          float p = __expf(s_acc[n][i] - mrun[i]);
          tsum[i] += p;
          Ps[w][4*g + i][16*n + m] = (bf16)p;
        }
#pragma unroll
      for (int i = 0; i < 4; ++i) {
        float s = tsum[i];
        s += __shfl_xor(s, 1);
        s += __shfl_xor(s, 2);
        s += __shfl_xor(s, 4);
        s += __shfl_xor(s, 8);
        lrun[i] = lrun[i] * corr[i] + s;
      }
#pragma unroll
      for (int n = 0; n < 4; ++n)
#pragma unroll
        for (int i = 0; i < 4; ++i) o_acc[n][i] *= corr[i];

#pragma unroll
      for (int kk = 0; kk < 2; ++kk) {
        bf16x8 pf = *(const bf16x8*)&Ps[w][m][kk*32 + g*8];
#pragma unroll
        for (int n = 0; n < 4; ++n) {
          bf16x8 vf = *(const bf16x8*)&VTs[w][16*n + m][kk*32 + g*8];
          o_acc[n] = MFMA16(pf, vf, o_acc[n]);
        }
      }

      if (!more) break;
      writeKV();
      j = jn;
    }
  }

  // ---- cross-wave merge of the two online-softmax partials ----
  float* PO = (float*)&Ks[w][0][0];
  float* PM = (float*)&VTs[w][0][0];
#pragma unroll
  for (int n = 0; n < 4; ++n)
#pragma unroll
    for (int i = 0; i < 4; ++i)
      PO[(4*g + i)*64 + 16*n + m] = o_acc[n][i];
  if (m == 0) {
#pragma unroll
    for (int i = 0; i < 4; ++i) {
      PM[4*g + i]      = mrun[i];
      PM[16 + 4*g + i] = lrun[i];
    }
  }
  __syncthreads();

  {
    const int r  = tid >> 3;
    const int c0 = (tid & 7) * 8;
    const float* O0 = (const float*)&Ks[0][0][0];
    const float* O1 = (const float*)&Ks[1][0][0];
    const float* M0 = (const float*)&VTs[0][0][0];
    const float* M1 = (const float*)&VTs[1][0][0];
    float m0 = M0[r], l0 = M0[16 + r];
    float m1 = M1[r], l1 = M1[16 + r];
    float mx = fmaxf(m0, m1);
    float s0 = __expf(m0 - mx), s1 = __expf(m1 - mx);
    float inv = 1.f / (s0*l0 + s1*l1);
    float4 x0 = *(const float4*)(O0 + r*64 + c0);
    float4 x1 = *(const float4*)(O0 + r*64 + c0 + 4);
    float4 y0 = *(const float4*)(O1 + r*64 + c0);
    float4 y1 = *(const float4*)(O1 + r*64 + c0 + 4);
    float4 o0, o1;
    o0.x=(x0.x*s0+y0.x*s1)*inv; o0.y=(x0.y*s0+y0.y*s1)*inv;
    o0.z=(x0.z*s0+y0.z*s1)*inv; o0.w=(x0.w*s0+y0.w*s1)*inv;
    o1.x=(x1.x*s0+y1.x*s1)*inv; o1.y=(x1.y*s0+y1.y*s1)*inv;
    o1.z=(x1.z*s0+y1.z*s1)*inv; o1.w=(x1.w*s0+y1.w*s1)*inv;
    float* op = out + ((size_t)b*SEQ + qt*16 + r) * HS + c0;
    *(float4*)(op)     = o0;
    *(float4*)(op + 4) = o1;
  }
}

extern "C" void kernel_launch(void* const* d_in, const int* in_sizes, int n_in,
                              void* d_out, int out_size, void* d_ws, size_t ws_size,
                              hipStream_t stream) {
  (void)in_sizes; (void)n_in; (void)out_size; (void)ws_size;
  const float* index  = (const float*)d_in[0];
  const float* memory = (const float*)d_in[1];
  const float* Wq     = (const float*)d_in[2];
  const float* Wk     = (const float*)d_in[3];
  const float* Wv     = (const float*)d_in[4];
  float* out = (float*)d_out;

  bf16* qb  = (bf16*)d_ws;                          // [NB*SEQ][64]
  bf16* kb  = qb  + (size_t)NB * SEQ * HS;          // [NB*SEQ][64]
  bf16* vtb = kb  + (size_t)NB * SEQ * HS;          // [NB][64][SEQ]
  bf16* wqb = vtb + (size_t)NB * SEQ * HS;          // [64][1024] (pre-scaled)
  bf16* wkb = wqb + (size_t)HS * NE;
  bf16* wvb = wkb + (size_t)HS * NE;

  wcvt_kernel<<<dim3(64), 256, 0, stream>>>(Wq, Wk, Wv, wqb, wkb, wvb);
  proj_kernel<<<dim3(512), 256, 0, stream>>>(index, memory, wqb, wkb, wvb, qb, kb, vtb);
  attn_kernel<<<dim3(128, 8), 128, 0, stream>>>(qb, kb, vtb, out);
}